// Round 5
// baseline (9513.854 us; speedup 1.0000x reference)
//
#include <hip/hip_runtime.h>
#include <hip/hip_bf16.h>

typedef __hip_bfloat16 bf16;

#define NB   16
#define HIN  32
#define WIN_ 32
#define C    512
#define HO   64
#define WO   64

__device__ __forceinline__ float b2f(bf16 v) { return __bfloat162float(v); }
__device__ __forceinline__ bf16  f2b(float v) { return __float2bfloat16(v); }
__device__ __forceinline__ float lrelu(float v) { return v > 0.f ? v : 0.2f * v; }

// s[b,co] = sum_ci w[b,ci]*fw[ci,co]*scale + fb[co]
__global__ __launch_bounds__(256) void style_fc_kernel(
    const float* __restrict__ w, const float* __restrict__ fw,
    const float* __restrict__ fb, float* __restrict__ s)
{
    int b = blockIdx.x;
    __shared__ float wrow[C];
    for (int i = threadIdx.x; i < C; i += 256) wrow[i] = w[b * C + i];
    __syncthreads();
    const float scale = 0.044194173824159216f;  // 1/sqrt(512)
    for (int co = threadIdx.x; co < C; co += 256) {
        float acc = 0.f;
        for (int ci = 0; ci < C; ci++)
            acc = fmaf(wrow[ci], fw[ci * C + co], acc);
        s[b * C + co] = acc * scale + fb[co];
    }
}

// g[b,co] = wscale * rsqrt(wscale^2 * sum_{tap,ci} W^2 * s^2 + 1e-8)
__global__ __launch_bounds__(512) void demod_kernel(
    const float* __restrict__ s, const float* __restrict__ cw,
    float* __restrict__ g, float wscale)
{
    int b = blockIdx.x;
    int co = threadIdx.x;
    __shared__ float s2[C];
    { float v = s[b * C + threadIdx.x]; s2[threadIdx.x] = v * v; }
    __syncthreads();
    float acc = 0.f;
    for (int t = 0; t < 9; t++) {
        const float* wt = cw + t * C * C;
        for (int ci = 0; ci < C; ci++) {
            float wv = wt[ci * C + co];   // coalesced across co
            acc = fmaf(wv * wv, s2[ci], acc);
        }
    }
    g[b * C + co] = wscale / sqrtf(acc * wscale * wscale + 1e-8f);
}

// Transposed conv 3x3 stride 2 SAME (no flip): out(oy,ox) gets tap (ky,kx) iff
// (oy+ky) even && (ox+kx) even, from in((oy+ky-2)/2,(ox+kx-2)/2). Writes t0 fp32.
__global__ __launch_bounds__(256) void conv1t_kernel(
    const float* __restrict__ x, const float* __restrict__ cw,
    const float* __restrict__ s1, const float* __restrict__ g1,
    float* __restrict__ t0)
{
    const int n0 = blockIdx.x * 64;
    const int oy = blockIdx.y;
    const int b  = blockIdx.z;
    const int tid = threadIdx.x;
    const int tx = tid & 15, ty = tid >> 4;

    __shared__ float As[32][68];
    __shared__ float Bs[32][68];
    __shared__ float srow[C];
    for (int i = tid; i < C; i += 256) srow[i] = s1[b * C + i];
    __syncthreads();

    float acc[4][4] = {};

    for (int ky = 0; ky < 3; ky++) {
        int t = oy + ky - 2;
        if (t & 1) continue;
        int iy = t >> 1;
        if (iy < 0 || iy >= HIN) continue;
        for (int kx = 0; kx < 3; kx++) {
            const float* wt = cw + (ky * 3 + kx) * C * C;
            for (int c0 = 0; c0 < C; c0 += 32) {
                #pragma unroll
                for (int l = 0; l < 8; l++) {
                    int idx = tid + l * 256;
                    int m = idx >> 5, k = idx & 31;
                    int u = m + kx - 2;
                    int ix = u >> 1;
                    float v = 0.f;
                    if (!(u & 1) && ix >= 0 && ix < WIN_)
                        v = x[((b * HIN + iy) * WIN_ + ix) * C + c0 + k] * srow[c0 + k];
                    As[k][m] = v;
                }
                #pragma unroll
                for (int l = 0; l < 8; l++) {
                    int idx = tid + l * 256;
                    int k = idx >> 6, n = idx & 63;
                    Bs[k][n] = wt[(c0 + k) * C + n0 + n];
                }
                __syncthreads();
                #pragma unroll 4
                for (int k = 0; k < 32; k++) {
                    float4 av = *(const float4*)&As[k][ty * 4];
                    float4 bv = *(const float4*)&Bs[k][tx * 4];
                    float a4[4] = {av.x, av.y, av.z, av.w};
                    float b4[4] = {bv.x, bv.y, bv.z, bv.w};
                    #pragma unroll
                    for (int i = 0; i < 4; i++)
                        #pragma unroll
                        for (int j = 0; j < 4; j++)
                            acc[i][j] = fmaf(a4[i], b4[j], acc[i][j]);
                }
                __syncthreads();
            }
        }
    }

    #pragma unroll
    for (int i = 0; i < 4; i++) {
        int m = ty * 4 + i;
        float* dst = t0 + ((size_t)(b * HO + oy) * WO + m) * C + n0 + tx * 4;
        #pragma unroll
        for (int j = 0; j < 4; j++)
            dst[j] = acc[i][j] * g1[b * C + n0 + tx * 4 + j];
    }
}

// 4x4 FIR blur ([1,3,3,1] outer /16, pads lo=1 hi=2) + noise + bias + lrelu -> x1 (bf16)
__global__ __launch_bounds__(256) void blur_kernel(
    const float* __restrict__ t0, const float* __restrict__ noise1,
    const float* __restrict__ sn1, const float* __restrict__ bias1,
    bf16* __restrict__ x1)
{
    const int ox = blockIdx.x, oy = blockIdx.y, b = blockIdx.z;
    const float nz = noise1[(b * HO + oy) * WO + ox];
    const int F[4] = {1, 3, 3, 1};
    for (int c0 = threadIdx.x; c0 < C; c0 += 256) {
        float acc = 0.f;
        #pragma unroll
        for (int i = 0; i < 4; i++) {
            int iy = oy + i - 1;
            if (iy < 0 || iy >= HO) continue;
            #pragma unroll
            for (int j = 0; j < 4; j++) {
                int ix = ox + j - 1;
                if (ix < 0 || ix >= WO) continue;
                acc = fmaf((float)(F[i] * F[j]),
                           t0[((size_t)(b * HO + iy) * WO + ix) * C + c0], acc);
            }
        }
        acc *= (1.f / 16.f);
        float v = acc + sn1[c0] * nz + bias1[c0];
        x1[((size_t)(b * HO + oy) * WO + ox) * C + c0] = f2b(lrelu(v));
    }
}

// 3x3 stride 1 SAME modulated conv + demod + noise + bias + lrelu -> x2 (fp32 d_out)
__global__ __launch_bounds__(256) void conv2_kernel(
    const bf16* __restrict__ x1, const float* __restrict__ cw,
    const float* __restrict__ s2, const float* __restrict__ g2,
    const float* __restrict__ noise2, const float* __restrict__ sn2,
    const float* __restrict__ bias2, float* __restrict__ out)
{
    const int n0 = blockIdx.x * 64;
    const int oy = blockIdx.y;
    const int b  = blockIdx.z;
    const int tid = threadIdx.x;
    const int tx = tid & 15, ty = tid >> 4;

    __shared__ float As[32][68];
    __shared__ float Bs[32][68];
    __shared__ float srow[C];
    for (int i = tid; i < C; i += 256) srow[i] = s2[b * C + i];
    __syncthreads();

    float acc[4][4] = {};

    for (int dy = 0; dy < 3; dy++) {
        int iy = oy + dy - 1;
        if (iy < 0 || iy >= HO) continue;
        for (int dx = 0; dx < 3; dx++) {
            const float* wt = cw + (dy * 3 + dx) * C * C;
            for (int c0 = 0; c0 < C; c0 += 32) {
                #pragma unroll
                for (int l = 0; l < 8; l++) {
                    int idx = tid + l * 256;
                    int m = idx >> 5, k = idx & 31;
                    int u = m + dx - 1;
                    float v = 0.f;
                    if (u >= 0 && u < WO)
                        v = b2f(x1[((size_t)(b * HO + iy) * WO + u) * C + c0 + k]) * srow[c0 + k];
                    As[k][m] = v;
                }
                #pragma unroll
                for (int l = 0; l < 8; l++) {
                    int idx = tid + l * 256;
                    int k = idx >> 6, n = idx & 63;
                    Bs[k][n] = wt[(c0 + k) * C + n0 + n];
                }
                __syncthreads();
                #pragma unroll 4
                for (int k = 0; k < 32; k++) {
                    float4 av = *(const float4*)&As[k][ty * 4];
                    float4 bv = *(const float4*)&Bs[k][tx * 4];
                    float a4[4] = {av.x, av.y, av.z, av.w};
                    float b4[4] = {bv.x, bv.y, bv.z, bv.w};
                    #pragma unroll
                    for (int i = 0; i < 4; i++)
                        #pragma unroll
                        for (int j = 0; j < 4; j++)
                            acc[i][j] = fmaf(a4[i], b4[j], acc[i][j]);
                }
                __syncthreads();
            }
        }
    }

    #pragma unroll
    for (int i = 0; i < 4; i++) {
        int m = ty * 4 + i;
        float nz = noise2[(b * HO + oy) * WO + m];
        float* dst = out + ((size_t)(b * HO + oy) * WO + m) * C + n0 + tx * 4;
        #pragma unroll
        for (int j = 0; j < 4; j++) {
            int co = n0 + tx * 4 + j;
            float v = acc[i][j] * g2[b * C + co] + sn2[co] * nz + bias2[co];
            dst[j] = lrelu(v);
        }
    }
}

// 1x1 conv (no demod) + bias + lrelu -> rgb (fp32). Recomputes its own style vector
// so it never reads the d_out-tail scratch it overwrites.
__global__ __launch_bounds__(256) void torgb_kernel(
    const float* __restrict__ x2, const float* __restrict__ w,
    const float* __restrict__ fw, const float* __restrict__ fb,
    const float* __restrict__ wr, const float* __restrict__ biasr,
    float* __restrict__ rgb)
{
    const int b = blockIdx.y;
    const int oy = blockIdx.x * 4 + (threadIdx.x >> 6);
    const int ox = threadIdx.x & 63;
    __shared__ float wrow[C];
    __shared__ float weff[C][3];
    for (int i = threadIdx.x; i < C; i += 256) wrow[i] = w[b * C + i];
    __syncthreads();
    const float scale = 0.044194173824159216f;  // 1/sqrt(512), fc scale AND 1x1 conv wscale
    for (int ci = threadIdx.x; ci < C; ci += 256) {
        float acc = 0.f;
        for (int k = 0; k < C; k++)
            acc = fmaf(wrow[k], fw[k * C + ci], acc);
        float s = acc * scale + fb[ci];
        float sc = scale * s;
        weff[ci][0] = sc * wr[ci * 3 + 0];
        weff[ci][1] = sc * wr[ci * 3 + 1];
        weff[ci][2] = sc * wr[ci * 3 + 2];
    }
    __syncthreads();
    const float* px = x2 + ((size_t)(b * HO + oy) * WO + ox) * C;
    float a0 = 0.f, a1 = 0.f, a2 = 0.f;
    for (int ci = 0; ci < C; ci++) {
        float f = px[ci];
        a0 = fmaf(f, weff[ci][0], a0);
        a1 = fmaf(f, weff[ci][1], a1);
        a2 = fmaf(f, weff[ci][2], a2);
    }
    float* dst = rgb + ((size_t)(b * HO + oy) * WO + ox) * 3;
    dst[0] = lrelu(a0 + biasr[0]);
    dst[1] = lrelu(a1 + biasr[1]);
    dst[2] = lrelu(a2 + biasr[2]);
}

extern "C" void kernel_launch(void* const* d_in, const int* in_sizes, int n_in,
                              void* d_out, int out_size, void* d_ws, size_t ws_size,
                              hipStream_t stream)
{
    (void)in_sizes; (void)n_in; (void)out_size; (void)ws_size;
    const float* x       = (const float*)d_in[0];
    const float* w       = (const float*)d_in[1];
    const float* noise1  = (const float*)d_in[2];
    const float* noise2  = (const float*)d_in[3];
    const float* fcl1_w  = (const float*)d_in[4];
    const float* fcl1_b  = (const float*)d_in[5];
    const float* conv1_w = (const float*)d_in[6];
    const float* sn1     = (const float*)d_in[7];
    const float* bias1   = (const float*)d_in[8];
    const float* fcl2_w  = (const float*)d_in[9];
    const float* fcl2_b  = (const float*)d_in[10];
    const float* conv2_w = (const float*)d_in[11];
    const float* sn2     = (const float*)d_in[12];
    const float* bias2   = (const float*)d_in[13];
    const float* fclr_w  = (const float*)d_in[14];
    const float* fclr_b  = (const float*)d_in[15];
    const float* convr_w = (const float*)d_in[16];
    const float* biasr   = (const float*)d_in[17];

    float* out_x2  = (float*)d_out;               // 16*64*64*512 fp32 = 128 MiB
    float* out_rgb = out_x2 + 33554432;           // 16*64*64*3 fp32 = 768 KiB

    // Small scratch in the rgb tail of d_out (dead until torgb; torgb only WRITES
    // there and recomputes its style itself): 4 * 32 KiB = 128 KiB <= 768 KiB.
    float* s1 = out_rgb;
    float* s2 = out_rgb + 8192;
    float* g1 = out_rgb + 16384;
    float* g2 = out_rgb + 24576;

    // d_ws usage: exactly 64 MiB — bf16 x1 only.
    bf16* x1 = (bf16*)d_ws;                       // 33554432 bf16 = 67108864 B

    float* t0 = out_x2;  // pre-blur conv1 output (fp32), overwritten by x2 later

    const float WS33 = 0.014731391274719739f;     // 1/sqrt(9*512)

    style_fc_kernel<<<NB, 256, 0, stream>>>(w, fcl1_w, fcl1_b, s1);
    style_fc_kernel<<<NB, 256, 0, stream>>>(w, fcl2_w, fcl2_b, s2);
    demod_kernel<<<NB, 512, 0, stream>>>(s1, conv1_w, g1, WS33);
    demod_kernel<<<NB, 512, 0, stream>>>(s2, conv2_w, g2, WS33);
    conv1t_kernel<<<dim3(8, 64, NB), 256, 0, stream>>>(x, conv1_w, s1, g1, t0);
    blur_kernel<<<dim3(64, 64, NB), 256, 0, stream>>>(t0, noise1, sn1, bias1, x1);
    conv2_kernel<<<dim3(8, 64, NB), 256, 0, stream>>>(x1, conv2_w, s2, g2, noise2, sn2, bias2, out_x2);
    torgb_kernel<<<dim3(16, NB), 256, 0, stream>>>(out_x2, w, fclr_w, fclr_b, convr_w, biasr, out_rgb);
}